// Round 9
// baseline (232.088 us; speedup 1.0000x reference)
//
#include <hip/hip_runtime.h>
#include <math.h>

typedef unsigned int u32;
typedef unsigned long long u64;

#define BB 4
#define AA 262144              // 1<<18
#define NN (BB*AA)
#define PRE 4000
#define POST 1000
#define CAP 4096               // crow/nbox row stride
#define CAPR 5632              // key slots per batch: G [0,4000) + E [4000,5632)
#define MASKW 64
#define NBLK 63                // ceil(4000/64) mask word-blocks
#define NCH64 63               // k_reduce: 64-row chunks
#define TROWS 4032             // transposed mask rows (63*64)
#define SLICES 64              // private hist slices per batch (no atomics)
#define RSLICE 8               // rank j-slices (occupancy for k_rankp)

// ---- workspace layout (bytes) ----
// [0, ZERO_END) zeroed by k_hcoarse's folded zero-pass.
static const size_t OFF_CNTG = 0;                          // int, stride 32 ints x4
static const size_t OFF_CNTE = 512;                        // int, stride 32 ints x4
static const size_t OFF_KEYS = 1024;                       // u64[4][5632] = 176 KiB
static const size_t OFF_RANK = OFF_KEYS + (size_t)BB*CAPR*8;       // u32[4][5632]
static const size_t ZERO_END = OFF_RANK + (size_t)BB*CAPR*4;       // 271360
static const size_t OFF_HC   = ZERO_END;                   // u32[4][64][256] = 256 KiB
static const size_t OFF_HF   = OFF_HC + 262144;            // u32[4][64][256] = 256 KiB
static const size_t OFF_CROW = OFF_HF + 262144 + 384;              // float[4][4096][8]
static const size_t OFF_NBOX = OFF_CROW + (size_t)BB*CAP*8*4;
static const size_t OFF_MASK = OFF_NBOX + (size_t)BB*CAP*8*4;      // u64[4][64][4000] = 8 MB
static const size_t OFF_TRAN = OFF_MASK + (size_t)BB*MASKW*PRE*8;  // u64[4][4032][64] = 8.26 MB

// f32 sigmoid via correctly-rounded double exp (bit-exact, order == value order).
__device__ __forceinline__ u32 sigmoid_bits(float x) {
  float e = (float)exp(-(double)x);
  float s = 1.0f / (1.0f + e);
  return __float_as_uint(s);     // s in (0,1): bits > 0
}

// Monotone u32 transform of float bits (sigmoid monotone in x -> same order).
__device__ __forceinline__ u32 mono_bits(float x) {
  u32 f = __float_as_uint(x);
  return (f & 0x80000000u) ? ~f : (f | 0x80000000u);
}

// ---- coarse pass: 8-bit hist into PRIVATE per-block slices (no global atomics).
// Also zeroes [0, ZERO_END) (counters+keys+rank) -- replaces the memset launch.
__global__ __launch_bounds__(256) void k_hcoarse(const float* __restrict__ obj,
                                                 u32* __restrict__ hc,
                                                 u64* __restrict__ zws) {
  __shared__ u32 lh[256*16];
  int tid = threadIdx.x;
  for (int i = tid; i < 256*16; i += 256) lh[i] = 0;
  int zidx = blockIdx.x*256 + tid;
  if (zidx < (int)(ZERO_END/8)) zws[zidx] = 0;     // folded memset (33920 u64)
  __syncthreads();
  size_t blockBase = (size_t)blockIdx.x * 4096;
  int rep = tid & 15;
  for (int k = 0; k < 16; ++k) {
    u32 tt = mono_bits(obj[blockBase + (size_t)k*256 + tid]);
    atomicAdd(&lh[(tt >> 24)*16 + rep], 1u);
  }
  __syncthreads();
  u32 s = 0;
  #pragma unroll
  for (int r = 0; r < 16; ++r) s += lh[tid*16 + r];
  hc[(size_t)blockIdx.x*256 + tid] = s;   // slice fully written, no memset needed
}

// ---- fine pass (res1 folded in: every block re-derives C from hc) ----
__global__ __launch_bounds__(256) void k_hfine(const float* __restrict__ obj,
                                               const u32* __restrict__ hc,
                                               u32* __restrict__ hf) {
  __shared__ u32 sum[256];
  __shared__ u32 lh[256];
  __shared__ u32 Cs;
  int tid = threadIdx.x;
  size_t blockBase = (size_t)blockIdx.x * 4096;
  int b = (int)(blockBase >> 18);
  {
    const u32* basep = hc + (size_t)b*SLICES*256;
    u32 s = 0;
    for (int k = 0; k < SLICES; ++k) s += basep[k*256 + tid];
    sum[tid] = s;
  }
  lh[tid] = 0;
  __syncthreads();
  if (tid == 0) {
    u32 acc = 0; int cs = 0;
    for (int i = 255; i >= 0; --i) {
      u32 c = sum[i];
      if (acc + c >= (u32)PRE) { cs = i; break; }
      acc += c;
    }
    Cs = (u32)cs;
  }
  __syncthreads();
  u32 C = Cs;
  for (int k = 0; k < 16; ++k) {
    u32 tt = mono_bits(obj[blockBase + (size_t)k*256 + tid]);
    if ((tt >> 24) == C) atomicAdd(&lh[(tt >> 16) & 255u], 1u);
  }
  __syncthreads();
  hf[(size_t)blockIdx.x*256 + tid] = lh[tid];
}

// ---- compact candidates (res1+res2 folded in) ----
// G (bin>P, provably <=3999) -> [0,4000); E (bins P-1,P) -> [4000,5632).
__global__ __launch_bounds__(256) void k_compact(const float* __restrict__ obj,
                                                 const u32* __restrict__ hc,
                                                 const u32* __restrict__ hf,
                                                 int* __restrict__ cntG,
                                                 int* __restrict__ cntE,
                                                 u64* __restrict__ keys) {
  __shared__ u32 sum[256];
  __shared__ u64 st[2048];            // G from front, E from back
  __shared__ int nG, nE, baseG, baseE;
  __shared__ u32 Cs, As, Ps;
  int tid = threadIdx.x;
  size_t blockBase = (size_t)blockIdx.x * 4096;
  int b = (int)(blockBase >> 18);
  // res1 re-derivation
  {
    const u32* basep = hc + (size_t)b*SLICES*256;
    u32 s = 0;
    for (int k = 0; k < SLICES; ++k) s += basep[k*256 + tid];
    sum[tid] = s;
  }
  if (tid == 0) { nG = 0; nE = 0; }
  __syncthreads();
  if (tid == 0) {
    u32 acc = 0; int cs = 0;
    for (int i = 255; i >= 0; --i) {
      u32 c = sum[i];
      if (acc + c >= (u32)PRE) { cs = i; break; }
      acc += c;
    }
    Cs = (u32)cs; As = acc;
  }
  __syncthreads();                     // tid0 done reading sum; Cs/As visible
  // res2 re-derivation (sum overwritten only after the sync above)
  {
    const u32* basep = hf + (size_t)b*SLICES*256;
    u32 s = 0;
    for (int k = 0; k < SLICES; ++k) s += basep[k*256 + tid];
    sum[tid] = s;
  }
  __syncthreads();
  if (tid == 0) {
    u32 acc = As; int fb = 0;
    for (int i = 255; i >= 0; --i) {
      u32 c = sum[i];
      if (acc + c >= (u32)PRE) { fb = i; break; }
      acc += c;
    }
    Ps = (Cs << 8) | (u32)fb;
  }
  __syncthreads();
  u32 P = Ps;
  // compact (unchanged, proven)
  for (int k = 0; k < 16; ++k) {
    size_t g = blockBase + (size_t)k*256 + tid;
    float x = obj[g];
    u32 tb = mono_bits(x) >> 16;
    if (tb + 1u >= P) {               // admit bins P-1, P, >P
      u32 m = sigmoid_bits(x);
      u64 key = ((u64)m << 32) | (u64)(AA - 1 - (u32)(g & (AA - 1)));
      if (tb > P) { int p = atomicAdd(&nG, 1); if (p < 1536) st[p] = key; }
      else        { int p = atomicAdd(&nE, 1); if (p < 512) st[2047 - p] = key; }
    }
  }
  __syncthreads();
  int ng = nG < 1536 ? nG : 1536;
  int ne = nE < 512 ? nE : 512;
  if (tid == 0) baseG = atomicAdd(&cntG[b*32], ng);
  if (tid == 1) baseE = atomicAdd(&cntE[b*32], ne);
  __syncthreads();
  for (int i = tid; i < ng; i += 256) {
    int p = baseG + i;
    if (p < 4000) keys[(size_t)b*CAPR + p] = st[i];          // G region [0,4000)
  }
  for (int i = tid; i < ne; i += 256) {
    int p = baseE + i;
    if (p < CAPR - 4000) keys[(size_t)b*CAPR + 4000 + p] = st[2047 - i]; // E region
  }
}

// ---- partial rank: sliced for occupancy (~11 waves/CU) ----
__global__ __launch_bounds__(64) void k_rankp(const u64* __restrict__ keys,
                                              u32* __restrict__ rank) {
  int b = blockIdx.z;
  int slot = blockIdx.x*64 + threadIdx.x;
  const u64* kb = keys + (size_t)b*CAPR;
  u64 myk = kb[slot];
  const ulonglong2* p2 = (const ulonglong2*)(kb + blockIdx.y*(CAPR/RSLICE));
  int r = 0;
  for (int base = 0; base < CAPR/(2*RSLICE); base += 16) {   // 22 batches of 16
    ulonglong2 v[16];
    #pragma unroll
    for (int k = 0; k < 16; ++k) v[k] = p2[base + k];
    #pragma unroll
    for (int k = 0; k < 16; ++k)
      r += (int)(v[k].x > myk) + (int)(v[k].y > myk);
  }
  if (r) atomicAdd(&rank[b*CAPR + slot], (u32)r);
}

// ---- decode top-4000 by final rank (data-parallel, unpinned) ----
__global__ __launch_bounds__(256) void k_decode(const u64* __restrict__ keys,
                                                const u32* __restrict__ rank,
                                                const float* __restrict__ reg,
                                                const float* __restrict__ anc,
                                                float* __restrict__ crow,
                                                float* __restrict__ nbox) {
  int t = blockIdx.x*256 + threadIdx.x;        // over BB*CAPR
  int b = t / CAPR, slot = t - b*CAPR;
  u64 myk = keys[(size_t)b*CAPR + slot];
  int rk = (int)rank[b*CAPR + slot];
  if (myk == 0 || rk >= PRE) return;           // padding or beyond top-4000
  u32 m = (u32)(myk >> 32);
  int idx = AA - 1 - (int)(myk & 0xFFFFFFFFull);
  float score = __uint_as_float(m);
  size_t g = ((size_t)b << 18) + (size_t)idx;
  const float* rg = reg + g*7;
  const float* an = anc + g*7;
  float xa=an[0], ya=an[1], za=an[2], wa=an[3], la=an[4], ha=an[5], ra=an[6];
  float dx=rg[0], dy=rg[1], dz=rg[2], dw=rg[3], dl=rg[4], dh=rg[5], dr=rg[6];
  float diag = sqrtf(wa*wa + la*la);
  float x = dx*diag + xa;
  float y = dy*diag + ya;
  float z = dz*ha + za;
  float w = expf(dw)*wa;
  float l = expf(dl)*la;
  float h = expf(dh)*ha;
  float r = dr + ra;
  float* cr = crow + ((size_t)b*CAP + rk)*8;
  cr[0]=x; cr[1]=y; cr[2]=z; cr[3]=w; cr[4]=l; cr[5]=h; cr[6]=r; cr[7]=score;
  float sx = fmaxf(w, 0.2f), sy = fmaxf(l, 0.2f), sz = fmaxf(h, 0.2f);
  float* nb = nbox + ((size_t)b*CAP + rk)*8;
  nb[0]=x - sx*0.5f; nb[1]=y - sy*0.5f; nb[2]=z;
  nb[3]=x + sx*0.5f; nb[4]=y + sy*0.5f; nb[5]=z + sz;
  nb[6]=sx*sy*sz;   nb[7]=0.f;
}

// ---- suppression bitmask, col-major (unpinned, full machine; PROVEN) ----
__global__ __launch_bounds__(256) void k_mask(const float* __restrict__ nbox,
                                              u64* __restrict__ mask) {
  int c = blockIdx.x;            // word/column block 0..62
  int R = blockIdx.y;            // 256-row tile 0..15
  int b = blockIdx.z;
  if (c < R*4) return;           // tile fully below diagonal: words never read
  __shared__ float4 ca4[64], cb4[64];
  int t = threadIdx.x;
  int j0 = c*64;
  if (t < 64) {
    int j = j0 + t; int jc = j < PRE ? j : 0;
    const float4* p = (const float4*)(nbox + ((size_t)b*CAP + jc)*8);
    ca4[t] = p[0]; cb4[t] = p[1];
  }
  __syncthreads();
  int i = R*256 + t;
  if (i >= PRE) return;
  const float4* rp = (const float4*)(nbox + ((size_t)b*CAP + i)*8);
  float4 A = rp[0], Bv = rp[1];  // A = lo.xyz, hi.x ; Bv = hi.y, hi.z, vol, pad
  u64 bits = 0;
  #pragma unroll
  for (int jj = 0; jj < 64; ++jj) {
    float4 C = ca4[jj], D = cb4[jj];
    float d0 = fminf(A.w,  C.w) - fmaxf(A.x, C.x);
    float d1 = fminf(Bv.x, D.x) - fmaxf(A.y, C.y);
    float d2 = fminf(Bv.y, D.y) - fmaxf(A.z, C.z);
    float inter = fmaxf(d0, 0.f) * fmaxf(d1, 0.f) * fmaxf(d2, 0.f);
    float uni = Bv.z + D.z - inter;
    if (inter > 0.3f * uni) bits |= (1ull << jj);
  }
  int vcols = PRE - j0;                                  // >= 32 for c <= 62
  if (vcols < 64) bits &= ((1ull << vcols) - 1ull);      // clear cols >= PRE
  if (j0 <= i) {                                          // clear cols j <= i
    int d = i - j0;
    if (d >= 63) bits = 0;
    else bits &= ~((2ull << d) - 1ull);
  }
  mask[((size_t)b*MASKW + c)*PRE + i] = bits;
}

// ---- R9: mask transpose, col-major -> row-major (coalesced both sides) ----
// R8 post-mortem model: k_reduce is bound by DISTINCT CACHE-LINE REQUESTS
// (~34k lines at ~2.9cy/line through one CU -- invariant across R0/R3/R8).
// The reduce needs only 16B per 128B line in col-major. This kernel repacks
// once, in parallel: block (b, n) transposes rows n*64..n*64+64 via LDS.
// Reads col-major 512B runs (single-writer lines from k_mask blocks);
// writes trans[b][row][word] 512B coalesced. XCD-pinned (gridDim.x=8, x=b)
// so batch b's trans lines are dirty in XCD b's L2, where k_reduce block b
// (grid=4, flat%8) reads them LOCALLY. k_reduce line count: 34k -> ~4.4k.
__global__ __launch_bounds__(256) void k_transp(const u64* __restrict__ mask,
                                                u64* __restrict__ trans) {
  __shared__ u64 st[64][65];           // +1 u64 pad: transposed read ~4-way max
  int b = blockIdx.x;                  // XCD pin; 4..7 exit
  if (b >= BB) return;
  int n = blockIdx.y;                  // row-stripe 0..62
  int t = threadIdx.x;
  int lane = t & 63, v = t >> 6;       // 4 waves
  // read: word w's rows n*64..n*64+64 (contiguous 512B). n=62, lane>=32 reads
  // garbage (rows>=PRE wrap into next word-column) -- in-bounds, masked later.
  #pragma unroll
  for (int k = 0; k < 16; ++k) {
    int w = v + 4*k;
    st[w][lane] = mask[((size_t)b*MASKW + w)*PRE + (size_t)n*64 + lane];
  }
  __syncthreads();
  // write: row r's 64 words contiguous (512B coalesced)
  #pragma unroll
  for (int k = 0; k < 16; ++k) {
    int r = v + 4*k;
    trans[((size_t)b*TROWS + (size_t)n*64 + r)*64 + lane] = st[lane][r];
  }
}

// ---- greedy NMS reduce: 64-row chunks from ROW-MAJOR trans (R9) ----
// load_chunk64r: 64 coalesced u64-loads (4 lines each) deliver the IDENTICAL
// register layout R8's resolve consumed: buf[jj] = word `lane` of row jj.
// Per chunk 256 lines (was 2048). Sub-diagonal garbage words (lane < c)
// zeroed as in R8. Last chunk masks rows >= PRE.
__device__ __forceinline__ void load_chunk64r(u64 (&buf)[64], const u64* rowsb,
                                              int c, int lane) {
  bool act = lane >= c;                // words < row>>6 never written by k_mask
  const u64* p = rowsb + (size_t)c*64*64 + lane;
  #pragma unroll
  for (int k = 0; k < 64; ++k) {
    u64 v = 0;
    if (act) v = p[(size_t)k*64];
    buf[k] = v;
  }
}

__device__ __forceinline__ void resolve_chunk64(u64 (&buf)[64], int c, int lane,
                                                u64& removed, int& kc,
                                                int* __restrict__ sel_lds) {
  u64 cur = removed, km = 0;
  #pragma unroll
  for (int jj = 0; jj < 64; ++jj) {
    if (((cur >> jj) & 1ull) == 0ull) {
      km |= (1ull << jj);
      cur |= buf[jj];
    }
  }
  if (c == NCH64 - 1) km &= 0xFFFFFFFFull;   // rows >= PRE invalid (trailing jj)
  u64 kmw = __shfl(km, c, 64);           // only lane c's km is meaningful
  #pragma unroll
  for (int jj = 0; jj < 64; ++jj) {
    if ((kmw >> jj) & 1ull) removed |= buf[jj];
  }
  bool mine = (kmw >> lane) & 1ull;
  int pos = kc + (int)__popcll(kmw & ((1ull << lane) - 1ull));
  if (mine && pos < POST) sel_lds[pos] = c*64 + lane;
  kc += (int)__popcll(kmw);              // uniform across wave
}

__global__ __launch_bounds__(64, 1) void k_reduce(const u64* __restrict__ trans,
                                                  const float* __restrict__ crow,
                                                  float* __restrict__ out) {
  __shared__ int sel_lds[POST];
  int b = blockIdx.x, lane = threadIdx.x;
  const u64* rowsb = trans + (size_t)b*TROWS*64;
  u64 bufA[64], bufB[64];
  u64 removed = 0;
  int kc = 0;
  load_chunk64r(bufA, rowsb, 0, lane);
  for (int c = 0; c < NCH64; c += 2) {
    if (c + 1 < NCH64) load_chunk64r(bufB, rowsb, c + 1, lane);   // prefetch
    resolve_chunk64(bufA, c, lane, removed, kc, sel_lds);
    if (kc >= POST) break;
    if (c + 1 >= NCH64) break;
    if (c + 2 < NCH64) load_chunk64r(bufA, rowsb, c + 2, lane);   // prefetch
    resolve_chunk64(bufB, c + 1, lane, removed, kc, sel_lds);
    if (kc >= POST) break;
  }
  __syncthreads();
  int kcap = kc < POST ? kc : POST;
  for (int r = lane; r < POST; r += 64) {
    float4 o0 = make_float4(0.f,0.f,0.f,0.f), o1 = o0;
    if (r < kcap) {
      int i = sel_lds[r];
      const float4* p = (const float4*)(crow + ((size_t)b*CAP + i)*8);
      o0 = p[0]; o1 = p[1];
    }
    float4* q = (float4*)(out + ((size_t)b*POST + r)*8);
    q[0] = o0; q[1] = o1;
  }
}

extern "C" void kernel_launch(void* const* d_in, const int* in_sizes, int n_in,
                              void* d_out, int out_size, void* d_ws, size_t ws_size,
                              hipStream_t stream) {
  const float* obj = (const float*)d_in[0];   // (N,)
  const float* reg = (const float*)d_in[1];   // (N,7)
  const float* anc = (const float*)d_in[2];   // (N,7)
  float* out = (float*)d_out;                 // (4,1000,8)
  char* ws = (char*)d_ws;

  int*  cntG = (int*)(ws + OFF_CNTG);
  int*  cntE = (int*)(ws + OFF_CNTE);
  u64*  keys = (u64*)(ws + OFF_KEYS);
  u32*  rank = (u32*)(ws + OFF_RANK);
  u32*  hc   = (u32*)(ws + OFF_HC);
  u32*  hf   = (u32*)(ws + OFF_HF);
  float* crow = (float*)(ws + OFF_CROW);
  float* nbox = (float*)(ws + OFF_NBOX);
  u64*  mask = (u64*)(ws + OFF_MASK);
  u64*  trans = (u64*)(ws + OFF_TRAN);

  // 8 launches. R9: k_transp repacks the mask row-major (coalesced, XCD-
  // pinned); k_reduce reads it with 8x fewer cache-line requests.
  k_hcoarse<<<NN/4096, 256, 0, stream>>>(obj, hc, (u64*)ws);
  k_hfine<<<NN/4096, 256, 0, stream>>>(obj, hc, hf);
  k_compact<<<NN/4096, 256, 0, stream>>>(obj, hc, hf, cntG, cntE, keys);
  k_rankp<<<dim3(CAPR/64, RSLICE, BB), 64, 0, stream>>>(keys, rank);
  k_decode<<<(BB*CAPR)/256, 256, 0, stream>>>(keys, rank, reg, anc, crow, nbox);
  k_mask<<<dim3(NBLK, 16, BB), 256, 0, stream>>>(nbox, mask);
  k_transp<<<dim3(8, NBLK), 256, 0, stream>>>(mask, trans);
  k_reduce<<<BB, 64, 0, stream>>>(trans, crow, out);
}

// Round 10
// 231.355 us; speedup vs baseline: 1.0032x; 1.0032x over previous
//
#include <hip/hip_runtime.h>
#include <math.h>

typedef unsigned int u32;
typedef unsigned long long u64;

#define BB 4
#define AA 262144              // 1<<18
#define NN (BB*AA)
#define PRE 4000
#define POST 1000
#define CAP 4096               // crow/nbox row stride
#define CAPR 5632              // key slots per batch: G [0,4000) + E [4000,5632)
#define MASKW 64
#define NBLK 63                // ceil(4000/64) mask word-blocks
#define NCHUNK 125             // 4000 / 32 exactly (reduce chunks)
#define SLICES 64              // private hist slices per batch (no atomics)
#define RSLICE 8               // rank j-slices (occupancy for k_rankp)

// ---- workspace layout (bytes) ----  (col-major mask; R5 layout)
// [0, ZERO_END) zeroed by k_hcoarse's folded zero-pass (memset launch removed).
static const size_t OFF_CNTG = 0;                          // int, stride 32 ints x4
static const size_t OFF_CNTE = 512;                        // int, stride 32 ints x4
static const size_t OFF_KEYS = 1024;                       // u64[4][5632] = 176 KiB
static const size_t OFF_RANK = OFF_KEYS + (size_t)BB*CAPR*8;       // u32[4][5632]
static const size_t ZERO_END = OFF_RANK + (size_t)BB*CAPR*4;       // 271360
static const size_t OFF_HC   = ZERO_END;                   // u32[4][64][256] = 256 KiB
static const size_t OFF_HF   = OFF_HC + 262144;            // u32[4][64][256] = 256 KiB
static const size_t OFF_CROW = OFF_HF + 262144 + 384;              // float[4][4096][8]
static const size_t OFF_NBOX = OFF_CROW + (size_t)BB*CAP*8*4;
static const size_t OFF_MASK = OFF_NBOX + (size_t)BB*CAP*8*4;      // u64[4][64][4000] = 8 MB

// f32 sigmoid via correctly-rounded double exp (bit-exact, order == value order).
__device__ __forceinline__ u32 sigmoid_bits(float x) {
  float e = (float)exp(-(double)x);
  float s = 1.0f / (1.0f + e);
  return __float_as_uint(s);     // s in (0,1): bits > 0
}

// Monotone u32 transform of float bits (sigmoid monotone in x -> same order).
__device__ __forceinline__ u32 mono_bits(float x) {
  u32 f = __float_as_uint(x);
  return (f & 0x80000000u) ? ~f : (f | 0x80000000u);
}

// ---- coarse pass: 8-bit hist into PRIVATE per-block slices (no global atomics).
// Also zeroes [0, ZERO_END) (counters+keys+rank) -- replaces the memset launch.
__global__ __launch_bounds__(256) void k_hcoarse(const float* __restrict__ obj,
                                                 u32* __restrict__ hc,
                                                 u64* __restrict__ zws) {
  __shared__ u32 lh[256*16];
  int tid = threadIdx.x;
  for (int i = tid; i < 256*16; i += 256) lh[i] = 0;
  int zidx = blockIdx.x*256 + tid;
  if (zidx < (int)(ZERO_END/8)) zws[zidx] = 0;     // folded memset (33920 u64)
  __syncthreads();
  size_t blockBase = (size_t)blockIdx.x * 4096;
  int rep = tid & 15;
  for (int k = 0; k < 16; ++k) {
    u32 tt = mono_bits(obj[blockBase + (size_t)k*256 + tid]);
    atomicAdd(&lh[(tt >> 24)*16 + rep], 1u);
  }
  __syncthreads();
  u32 s = 0;
  #pragma unroll
  for (int r = 0; r < 16; ++r) s += lh[tid*16 + r];
  hc[(size_t)blockIdx.x*256 + tid] = s;   // slice fully written, no memset needed
}

// ---- fine pass (res1 folded in: every block re-derives C from hc) ----
__global__ __launch_bounds__(256) void k_hfine(const float* __restrict__ obj,
                                               const u32* __restrict__ hc,
                                               u32* __restrict__ hf) {
  __shared__ u32 sum[256];
  __shared__ u32 lh[256];
  __shared__ u32 Cs;
  int tid = threadIdx.x;
  size_t blockBase = (size_t)blockIdx.x * 4096;
  int b = (int)(blockBase >> 18);
  {
    const u32* basep = hc + (size_t)b*SLICES*256;
    u32 s = 0;
    for (int k = 0; k < SLICES; ++k) s += basep[k*256 + tid];
    sum[tid] = s;
  }
  lh[tid] = 0;
  __syncthreads();
  if (tid == 0) {
    u32 acc = 0; int cs = 0;
    for (int i = 255; i >= 0; --i) {
      u32 c = sum[i];
      if (acc + c >= (u32)PRE) { cs = i; break; }
      acc += c;
    }
    Cs = (u32)cs;
  }
  __syncthreads();
  u32 C = Cs;
  for (int k = 0; k < 16; ++k) {
    u32 tt = mono_bits(obj[blockBase + (size_t)k*256 + tid]);
    if ((tt >> 24) == C) atomicAdd(&lh[(tt >> 16) & 255u], 1u);
  }
  __syncthreads();
  hf[(size_t)blockIdx.x*256 + tid] = lh[tid];
}

// ---- compact candidates (res1+res2 folded in) ----
// G (bin>P, provably <=3999) -> [0,4000); E (bins P-1,P) -> [4000,5632).
__global__ __launch_bounds__(256) void k_compact(const float* __restrict__ obj,
                                                 const u32* __restrict__ hc,
                                                 const u32* __restrict__ hf,
                                                 int* __restrict__ cntG,
                                                 int* __restrict__ cntE,
                                                 u64* __restrict__ keys) {
  __shared__ u32 sum[256];
  __shared__ u64 st[2048];            // G from front, E from back
  __shared__ int nG, nE, baseG, baseE;
  __shared__ u32 Cs, As, Ps;
  int tid = threadIdx.x;
  size_t blockBase = (size_t)blockIdx.x * 4096;
  int b = (int)(blockBase >> 18);
  // res1 re-derivation
  {
    const u32* basep = hc + (size_t)b*SLICES*256;
    u32 s = 0;
    for (int k = 0; k < SLICES; ++k) s += basep[k*256 + tid];
    sum[tid] = s;
  }
  if (tid == 0) { nG = 0; nE = 0; }
  __syncthreads();
  if (tid == 0) {
    u32 acc = 0; int cs = 0;
    for (int i = 255; i >= 0; --i) {
      u32 c = sum[i];
      if (acc + c >= (u32)PRE) { cs = i; break; }
      acc += c;
    }
    Cs = (u32)cs; As = acc;
  }
  __syncthreads();                     // tid0 done reading sum; Cs/As visible
  // res2 re-derivation (sum overwritten only after the sync above)
  {
    const u32* basep = hf + (size_t)b*SLICES*256;
    u32 s = 0;
    for (int k = 0; k < SLICES; ++k) s += basep[k*256 + tid];
    sum[tid] = s;
  }
  __syncthreads();
  if (tid == 0) {
    u32 acc = As; int fb = 0;
    for (int i = 255; i >= 0; --i) {
      u32 c = sum[i];
      if (acc + c >= (u32)PRE) { fb = i; break; }
      acc += c;
    }
    Ps = (Cs << 8) | (u32)fb;
  }
  __syncthreads();
  u32 P = Ps;
  // compact (unchanged, proven)
  for (int k = 0; k < 16; ++k) {
    size_t g = blockBase + (size_t)k*256 + tid;
    float x = obj[g];
    u32 tb = mono_bits(x) >> 16;
    if (tb + 1u >= P) {               // admit bins P-1, P, >P
      u32 m = sigmoid_bits(x);
      u64 key = ((u64)m << 32) | (u64)(AA - 1 - (u32)(g & (AA - 1)));
      if (tb > P) { int p = atomicAdd(&nG, 1); if (p < 1536) st[p] = key; }
      else        { int p = atomicAdd(&nE, 1); if (p < 512) st[2047 - p] = key; }
    }
  }
  __syncthreads();
  int ng = nG < 1536 ? nG : 1536;
  int ne = nE < 512 ? nE : 512;
  if (tid == 0) baseG = atomicAdd(&cntG[b*32], ng);
  if (tid == 1) baseE = atomicAdd(&cntE[b*32], ne);
  __syncthreads();
  for (int i = tid; i < ng; i += 256) {
    int p = baseG + i;
    if (p < 4000) keys[(size_t)b*CAPR + p] = st[i];          // G region [0,4000)
  }
  for (int i = tid; i < ne; i += 256) {
    int p = baseE + i;
    if (p < CAPR - 4000) keys[(size_t)b*CAPR + 4000 + p] = st[2047 - i]; // E region
  }
}

// ---- partial rank: sliced for occupancy (~11 waves/CU) ----
__global__ __launch_bounds__(64) void k_rankp(const u64* __restrict__ keys,
                                              u32* __restrict__ rank) {
  int b = blockIdx.z;
  int slot = blockIdx.x*64 + threadIdx.x;
  const u64* kb = keys + (size_t)b*CAPR;
  u64 myk = kb[slot];
  const ulonglong2* p2 = (const ulonglong2*)(kb + blockIdx.y*(CAPR/RSLICE));
  int r = 0;
  for (int base = 0; base < CAPR/(2*RSLICE); base += 16) {   // 22 batches of 16
    ulonglong2 v[16];
    #pragma unroll
    for (int k = 0; k < 16; ++k) v[k] = p2[base + k];
    #pragma unroll
    for (int k = 0; k < 16; ++k)
      r += (int)(v[k].x > myk) + (int)(v[k].y > myk);
  }
  if (r) atomicAdd(&rank[b*CAPR + slot], (u32)r);
}

// ---- decode top-4000 by final rank (data-parallel, unpinned) ----
__global__ __launch_bounds__(256) void k_decode(const u64* __restrict__ keys,
                                                const u32* __restrict__ rank,
                                                const float* __restrict__ reg,
                                                const float* __restrict__ anc,
                                                float* __restrict__ crow,
                                                float* __restrict__ nbox) {
  int t = blockIdx.x*256 + threadIdx.x;        // over BB*CAPR
  int b = t / CAPR, slot = t - b*CAPR;
  u64 myk = keys[(size_t)b*CAPR + slot];
  int rk = (int)rank[b*CAPR + slot];
  if (myk == 0 || rk >= PRE) return;           // padding or beyond top-4000
  u32 m = (u32)(myk >> 32);
  int idx = AA - 1 - (int)(myk & 0xFFFFFFFFull);
  float score = __uint_as_float(m);
  size_t g = ((size_t)b << 18) + (size_t)idx;
  const float* rg = reg + g*7;
  const float* an = anc + g*7;
  float xa=an[0], ya=an[1], za=an[2], wa=an[3], la=an[4], ha=an[5], ra=an[6];
  float dx=rg[0], dy=rg[1], dz=rg[2], dw=rg[3], dl=rg[4], dh=rg[5], dr=rg[6];
  float diag = sqrtf(wa*wa + la*la);
  float x = dx*diag + xa;
  float y = dy*diag + ya;
  float z = dz*ha + za;
  float w = expf(dw)*wa;
  float l = expf(dl)*la;
  float h = expf(dh)*ha;
  float r = dr + ra;
  float* cr = crow + ((size_t)b*CAP + rk)*8;
  cr[0]=x; cr[1]=y; cr[2]=z; cr[3]=w; cr[4]=l; cr[5]=h; cr[6]=r; cr[7]=score;
  float sx = fmaxf(w, 0.2f), sy = fmaxf(l, 0.2f), sz = fmaxf(h, 0.2f);
  float* nb = nbox + ((size_t)b*CAP + rk)*8;
  nb[0]=x - sx*0.5f; nb[1]=y - sy*0.5f; nb[2]=z;
  nb[3]=x + sx*0.5f; nb[4]=y + sy*0.5f; nb[5]=z + sz;
  nb[6]=sx*sy*sz;   nb[7]=0.f;
}

// ---- suppression bitmask, col-major mask[b][word c][row i] (proven) ----
__global__ __launch_bounds__(256) void k_mask(const float* __restrict__ nbox,
                                              u64* __restrict__ mask) {
  int c = blockIdx.x;            // word/column block 0..62
  int R = blockIdx.y;            // 256-row tile 0..15
  int b = blockIdx.z;
  if (c < R*4) return;           // tile fully below diagonal: words never read
  __shared__ float4 ca4[64], cb4[64];
  int t = threadIdx.x;
  int j0 = c*64;
  if (t < 64) {
    int j = j0 + t; int jc = j < PRE ? j : 0;
    const float4* p = (const float4*)(nbox + ((size_t)b*CAP + jc)*8);
    ca4[t] = p[0]; cb4[t] = p[1];
  }
  __syncthreads();
  int i = R*256 + t;
  if (i >= PRE) return;
  const float4* rp = (const float4*)(nbox + ((size_t)b*CAP + i)*8);
  float4 A = rp[0], Bv = rp[1];  // A = lo.xyz, hi.x ; Bv = hi.y, hi.z, vol, pad
  u64 bits = 0;
  #pragma unroll
  for (int jj = 0; jj < 64; ++jj) {
    float4 C = ca4[jj], D = cb4[jj];
    float d0 = fminf(A.w,  C.w) - fmaxf(A.x, C.x);
    float d1 = fminf(Bv.x, D.x) - fmaxf(A.y, C.y);
    float d2 = fminf(Bv.y, D.y) - fmaxf(A.z, C.z);
    float inter = fmaxf(d0, 0.f) * fmaxf(d1, 0.f) * fmaxf(d2, 0.f);
    float uni = Bv.z + D.z - inter;
    if (inter > 0.3f * uni) bits |= (1ull << jj);
  }
  int vcols = PRE - j0;                                  // >= 32 for c <= 62
  if (vcols < 64) bits &= ((1ull << vcols) - 1ull);      // clear cols >= PRE
  if (j0 <= i) {                                          // clear cols j <= i
    int d = i - j0;
    if (d >= 63) bits = 0;
    else bits &= ~((2ull << d) - 1ull);
  }
  mask[((size_t)b*MASKW + c)*PRE + i] = bits;
}

// ---- greedy NMS reduce, 32-row double-buffer with PINNED prefetch (R10) ----
// R9 post-mortem: per-chunk cost tracks ~150-200cy PER VMEM INSTRUCTION in
// every variant (R5 16 instr->2.8k cy, R8 32->6.4k, R9 64->7.6k) => loads pay
// near-full latency EACH. Root cause in the counters: R5's VGPR_Count=108 <
// 128 needed for two live u64[32] buffers -- the compiler SANK each load to
// its use, silently deleting the double-buffer in R0/R3/R4/R5/R8/R9 alike.
// Fix: (1) sched_barrier(0) after every load_chunk pins the load cluster
// before the resolve (rule #18); (2) loads made UNCONDITIONAL (address always
// in-bounds; `act` zero-mask applied by select AFTER the load) so predication
// can't block hoisting; (3) __launch_bounds__(64,1) gives VGPR headroom
// (~230 needed, spill-free <=450 per m08). Success check: VGPR >= 200.
__device__ __forceinline__ void load_chunk(u64 (&buf)[32], const u64* col,
                                           int c, int lane) {
  bool act = lane >= (c >> 1);           // words < row>>6 never written
  const ulonglong2* p = (const ulonglong2*)(col + c*32);
  #pragma unroll
  for (int k = 0; k < 16; ++k) {
    ulonglong2 v = p[k];                 // unconditional: hoistable
    buf[2*k]   = act ? v.x : 0;
    buf[2*k+1] = act ? v.y : 0;
  }
}

__device__ __forceinline__ void resolve_chunk(u64 (&buf)[32], int c, int lane,
                                              u64& removed, int& kc,
                                              int* __restrict__ sel_lds) {
  int wq = c >> 1;
  int base = (c & 1) * 32;               // bit window of word wq for this chunk
  u64 cur = removed, km = 0;
  #pragma unroll
  for (int jj = 0; jj < 32; ++jj) {
    if (((cur >> (base + jj)) & 1ull) == 0ull) {
      km |= (1ull << (base + jj));
      cur |= buf[jj];
    }
  }
  u64 kmw = __shfl(km, wq, 64);          // only lane wq's km is meaningful
  #pragma unroll
  for (int jj = 0; jj < 32; ++jj) {
    if ((kmw >> (base + jj)) & 1ull) removed |= buf[jj];
  }
  int sh = base + (lane & 31);           // <= 63: no UB shift
  bool mine = (lane < 32) && ((kmw >> sh) & 1ull);
  int pos = kc + (int)__popcll(kmw & ((1ull << sh) - 1ull));
  if (mine && pos < POST) sel_lds[pos] = c*32 + lane;
  kc += (int)__popcll(kmw);              // uniform across wave
}

__global__ __launch_bounds__(64, 1) void k_reduce(const u64* __restrict__ mask,
                                                  const float* __restrict__ crow,
                                                  float* __restrict__ out) {
  __shared__ int sel_lds[POST];
  int b = blockIdx.x, lane = threadIdx.x;
  const u64* col = mask + ((size_t)b*MASKW + lane)*PRE;   // this lane's word-column
  u64 bufA[32], bufB[32];
  u64 removed = 0;
  int kc = 0;
  load_chunk(bufA, col, 0, lane);
  __builtin_amdgcn_sched_barrier(0);     // pin: bufA loads issued HERE
  for (int c = 0; c < NCHUNK; c += 2) {
    if (c + 1 < NCHUNK) load_chunk(bufB, col, c + 1, lane);   // prefetch
    __builtin_amdgcn_sched_barrier(0);   // pin: bufB loads before resolve(A)
    resolve_chunk(bufA, c, lane, removed, kc, sel_lds);
    if (kc >= POST) break;
    if (c + 1 >= NCHUNK) break;
    if (c + 2 < NCHUNK) load_chunk(bufA, col, c + 2, lane);   // prefetch
    __builtin_amdgcn_sched_barrier(0);   // pin: bufA loads before resolve(B)
    resolve_chunk(bufB, c + 1, lane, removed, kc, sel_lds);
    if (kc >= POST) break;
  }
  __syncthreads();
  int kcap = kc < POST ? kc : POST;
  for (int r = lane; r < POST; r += 64) {
    float4 o0 = make_float4(0.f,0.f,0.f,0.f), o1 = o0;
    if (r < kcap) {
      int i = sel_lds[r];
      const float4* p = (const float4*)(crow + ((size_t)b*CAP + i)*8);
      o0 = p[0]; o1 = p[1];
    }
    float4* q = (float4*)(out + ((size_t)b*POST + r)*8);
    q[0] = o0; q[1] = o1;
  }
}

extern "C" void kernel_launch(void* const* d_in, const int* in_sizes, int n_in,
                              void* d_out, int out_size, void* d_ws, size_t ws_size,
                              hipStream_t stream) {
  const float* obj = (const float*)d_in[0];   // (N,)
  const float* reg = (const float*)d_in[1];   // (N,7)
  const float* anc = (const float*)d_in[2];   // (N,7)
  float* out = (float*)d_out;                 // (4,1000,8)
  char* ws = (char*)d_ws;

  int*  cntG = (int*)(ws + OFF_CNTG);
  int*  cntE = (int*)(ws + OFF_CNTE);
  u64*  keys = (u64*)(ws + OFF_KEYS);
  u32*  rank = (u32*)(ws + OFF_RANK);
  u32*  hc   = (u32*)(ws + OFF_HC);
  u32*  hf   = (u32*)(ws + OFF_HF);
  float* crow = (float*)(ws + OFF_CROW);
  float* nbox = (float*)(ws + OFF_NBOX);
  u64*  mask = (u64*)(ws + OFF_MASK);

  // 7 launches (R5 structure, timed-best 218us). R10: k_reduce's prefetch
  // actually pinned (sched_barrier + unconditional loads + (64,1) bounds).
  k_hcoarse<<<NN/4096, 256, 0, stream>>>(obj, hc, (u64*)ws);
  k_hfine<<<NN/4096, 256, 0, stream>>>(obj, hc, hf);
  k_compact<<<NN/4096, 256, 0, stream>>>(obj, hc, hf, cntG, cntE, keys);
  k_rankp<<<dim3(CAPR/64, RSLICE, BB), 64, 0, stream>>>(keys, rank);
  k_decode<<<(BB*CAPR)/256, 256, 0, stream>>>(keys, rank, reg, anc, crow, nbox);
  k_mask<<<dim3(NBLK, 16, BB), 256, 0, stream>>>(nbox, mask);
  k_reduce<<<BB, 64, 0, stream>>>(mask, crow, out);
}

// Round 12
// 218.060 us; speedup vs baseline: 1.0643x; 1.0610x over previous
//
#include <hip/hip_runtime.h>
#include <math.h>

typedef unsigned int u32;
typedef unsigned long long u64;

#define BB 4
#define AA 262144              // 1<<18
#define NN (BB*AA)
#define PRE 4000
#define POST 1000
#define CAP 4096               // crow/nbox row stride
#define CAPR 5632              // key slots per batch: G [0,4000) + E [4000,5632)
#define MASKW 64
#define NBLK 63                // ceil(4000/64) mask word-blocks
#define NCHUNK 125             // 4000 / 32 exactly (reduce chunks)
#define SLICES 64              // private hist slices per batch (no atomics)
#define RSLICE 8               // rank j-slices (occupancy for k_rankp)
#define PULLROWS 2048          // k_pull: rows staged into local XCD L2 (2x margin
                               // over the ~1056-row early-exit point, FETCH evidence)

// ---- workspace layout (bytes) ----  (col-major mask; R5 layout)
// [0, ZERO_END) zeroed by k_hcoarse's folded zero-pass (memset launch removed).
static const size_t OFF_CNTG = 0;                          // int, stride 32 ints x4
static const size_t OFF_CNTE = 512;                        // int, stride 32 ints x4
static const size_t OFF_KEYS = 1024;                       // u64[4][5632] = 176 KiB
static const size_t OFF_RANK = OFF_KEYS + (size_t)BB*CAPR*8;       // u32[4][5632]
static const size_t ZERO_END = OFF_RANK + (size_t)BB*CAPR*4;       // 271360
static const size_t OFF_HC   = ZERO_END;                   // u32[4][64][256] = 256 KiB
static const size_t OFF_HF   = OFF_HC + 262144;            // u32[4][64][256] = 256 KiB
static const size_t OFF_CROW = OFF_HF + 262144 + 384;              // float[4][4096][8]
static const size_t OFF_NBOX = OFF_CROW + (size_t)BB*CAP*8*4;
static const size_t OFF_MASK = OFF_NBOX + (size_t)BB*CAP*8*4;      // u64[4][64][4000] = 8 MB

// f32 sigmoid via correctly-rounded double exp (bit-exact, order == value order).
__device__ __forceinline__ u32 sigmoid_bits(float x) {
  float e = (float)exp(-(double)x);
  float s = 1.0f / (1.0f + e);
  return __float_as_uint(s);     // s in (0,1): bits > 0
}

// Monotone u32 transform of float bits (sigmoid monotone in x -> same order).
__device__ __forceinline__ u32 mono_bits(float x) {
  u32 f = __float_as_uint(x);
  return (f & 0x80000000u) ? ~f : (f | 0x80000000u);
}

// ---- coarse pass: 8-bit hist into PRIVATE per-block slices (no global atomics).
// Also zeroes [0, ZERO_END) (counters+keys+rank) -- replaces the memset launch.
__global__ __launch_bounds__(256) void k_hcoarse(const float* __restrict__ obj,
                                                 u32* __restrict__ hc,
                                                 u64* __restrict__ zws) {
  __shared__ u32 lh[256*16];
  int tid = threadIdx.x;
  for (int i = tid; i < 256*16; i += 256) lh[i] = 0;
  int zidx = blockIdx.x*256 + tid;
  if (zidx < (int)(ZERO_END/8)) zws[zidx] = 0;     // folded memset (33920 u64)
  __syncthreads();
  size_t blockBase = (size_t)blockIdx.x * 4096;
  int rep = tid & 15;
  for (int k = 0; k < 16; ++k) {
    u32 tt = mono_bits(obj[blockBase + (size_t)k*256 + tid]);
    atomicAdd(&lh[(tt >> 24)*16 + rep], 1u);
  }
  __syncthreads();
  u32 s = 0;
  #pragma unroll
  for (int r = 0; r < 16; ++r) s += lh[tid*16 + r];
  hc[(size_t)blockIdx.x*256 + tid] = s;   // slice fully written, no memset needed
}

// ---- fine pass (res1 folded in: every block re-derives C from hc) ----
__global__ __launch_bounds__(256) void k_hfine(const float* __restrict__ obj,
                                               const u32* __restrict__ hc,
                                               u32* __restrict__ hf) {
  __shared__ u32 sum[256];
  __shared__ u32 lh[256];
  __shared__ u32 Cs;
  int tid = threadIdx.x;
  size_t blockBase = (size_t)blockIdx.x * 4096;
  int b = (int)(blockBase >> 18);
  {
    const u32* basep = hc + (size_t)b*SLICES*256;
    u32 s = 0;
    for (int k = 0; k < SLICES; ++k) s += basep[k*256 + tid];
    sum[tid] = s;
  }
  lh[tid] = 0;
  __syncthreads();
  if (tid == 0) {
    u32 acc = 0; int cs = 0;
    for (int i = 255; i >= 0; --i) {
      u32 c = sum[i];
      if (acc + c >= (u32)PRE) { cs = i; break; }
      acc += c;
    }
    Cs = (u32)cs;
  }
  __syncthreads();
  u32 C = Cs;
  for (int k = 0; k < 16; ++k) {
    u32 tt = mono_bits(obj[blockBase + (size_t)k*256 + tid]);
    if ((tt >> 24) == C) atomicAdd(&lh[(tt >> 16) & 255u], 1u);
  }
  __syncthreads();
  hf[(size_t)blockIdx.x*256 + tid] = lh[tid];
}

// ---- compact candidates (res1+res2 folded in) ----
// G (bin>P, provably <=3999) -> [0,4000); E (bins P-1,P) -> [4000,5632).
__global__ __launch_bounds__(256) void k_compact(const float* __restrict__ obj,
                                                 const u32* __restrict__ hc,
                                                 const u32* __restrict__ hf,
                                                 int* __restrict__ cntG,
                                                 int* __restrict__ cntE,
                                                 u64* __restrict__ keys) {
  __shared__ u32 sum[256];
  __shared__ u64 st[2048];            // G from front, E from back
  __shared__ int nG, nE, baseG, baseE;
  __shared__ u32 Cs, As, Ps;
  int tid = threadIdx.x;
  size_t blockBase = (size_t)blockIdx.x * 4096;
  int b = (int)(blockBase >> 18);
  // res1 re-derivation
  {
    const u32* basep = hc + (size_t)b*SLICES*256;
    u32 s = 0;
    for (int k = 0; k < SLICES; ++k) s += basep[k*256 + tid];
    sum[tid] = s;
  }
  if (tid == 0) { nG = 0; nE = 0; }
  __syncthreads();
  if (tid == 0) {
    u32 acc = 0; int cs = 0;
    for (int i = 255; i >= 0; --i) {
      u32 c = sum[i];
      if (acc + c >= (u32)PRE) { cs = i; break; }
      acc += c;
    }
    Cs = (u32)cs; As = acc;
  }
  __syncthreads();                     // tid0 done reading sum; Cs/As visible
  // res2 re-derivation (sum overwritten only after the sync above)
  {
    const u32* basep = hf + (size_t)b*SLICES*256;
    u32 s = 0;
    for (int k = 0; k < SLICES; ++k) s += basep[k*256 + tid];
    sum[tid] = s;
  }
  __syncthreads();
  if (tid == 0) {
    u32 acc = As; int fb = 0;
    for (int i = 255; i >= 0; --i) {
      u32 c = sum[i];
      if (acc + c >= (u32)PRE) { fb = i; break; }
      acc += c;
    }
    Ps = (Cs << 8) | (u32)fb;
  }
  __syncthreads();
  u32 P = Ps;
  // compact (unchanged, proven)
  for (int k = 0; k < 16; ++k) {
    size_t g = blockBase + (size_t)k*256 + tid;
    float x = obj[g];
    u32 tb = mono_bits(x) >> 16;
    if (tb + 1u >= P) {               // admit bins P-1, P, >P
      u32 m = sigmoid_bits(x);
      u64 key = ((u64)m << 32) | (u64)(AA - 1 - (u32)(g & (AA - 1)));
      if (tb > P) { int p = atomicAdd(&nG, 1); if (p < 1536) st[p] = key; }
      else        { int p = atomicAdd(&nE, 1); if (p < 512) st[2047 - p] = key; }
    }
  }
  __syncthreads();
  int ng = nG < 1536 ? nG : 1536;
  int ne = nE < 512 ? nE : 512;
  if (tid == 0) baseG = atomicAdd(&cntG[b*32], ng);
  if (tid == 1) baseE = atomicAdd(&cntE[b*32], ne);
  __syncthreads();
  for (int i = tid; i < ng; i += 256) {
    int p = baseG + i;
    if (p < 4000) keys[(size_t)b*CAPR + p] = st[i];          // G region [0,4000)
  }
  for (int i = tid; i < ne; i += 256) {
    int p = baseE + i;
    if (p < CAPR - 4000) keys[(size_t)b*CAPR + 4000 + p] = st[2047 - i]; // E region
  }
}

// ---- partial rank: sliced for occupancy (~11 waves/CU) ----
__global__ __launch_bounds__(64) void k_rankp(const u64* __restrict__ keys,
                                              u32* __restrict__ rank) {
  int b = blockIdx.z;
  int slot = blockIdx.x*64 + threadIdx.x;
  const u64* kb = keys + (size_t)b*CAPR;
  u64 myk = kb[slot];
  const ulonglong2* p2 = (const ulonglong2*)(kb + blockIdx.y*(CAPR/RSLICE));
  int r = 0;
  for (int base = 0; base < CAPR/(2*RSLICE); base += 16) {   // 22 batches of 16
    ulonglong2 v[16];
    #pragma unroll
    for (int k = 0; k < 16; ++k) v[k] = p2[base + k];
    #pragma unroll
    for (int k = 0; k < 16; ++k)
      r += (int)(v[k].x > myk) + (int)(v[k].y > myk);
  }
  if (r) atomicAdd(&rank[b*CAPR + slot], (u32)r);
}

// ---- decode top-4000 by final rank (data-parallel, unpinned) ----
__global__ __launch_bounds__(256) void k_decode(const u64* __restrict__ keys,
                                                const u32* __restrict__ rank,
                                                const float* __restrict__ reg,
                                                const float* __restrict__ anc,
                                                float* __restrict__ crow,
                                                float* __restrict__ nbox) {
  int t = blockIdx.x*256 + threadIdx.x;        // over BB*CAPR
  int b = t / CAPR, slot = t - b*CAPR;
  u64 myk = keys[(size_t)b*CAPR + slot];
  int rk = (int)rank[b*CAPR + slot];
  if (myk == 0 || rk >= PRE) return;           // padding or beyond top-4000
  u32 m = (u32)(myk >> 32);
  int idx = AA - 1 - (int)(myk & 0xFFFFFFFFull);
  float score = __uint_as_float(m);
  size_t g = ((size_t)b << 18) + (size_t)idx;
  const float* rg = reg + g*7;
  const float* an = anc + g*7;
  float xa=an[0], ya=an[1], za=an[2], wa=an[3], la=an[4], ha=an[5], ra=an[6];
  float dx=rg[0], dy=rg[1], dz=rg[2], dw=rg[3], dl=rg[4], dh=rg[5], dr=rg[6];
  float diag = sqrtf(wa*wa + la*la);
  float x = dx*diag + xa;
  float y = dy*diag + ya;
  float z = dz*ha + za;
  float w = expf(dw)*wa;
  float l = expf(dl)*la;
  float h = expf(dh)*ha;
  float r = dr + ra;
  float* cr = crow + ((size_t)b*CAP + rk)*8;
  cr[0]=x; cr[1]=y; cr[2]=z; cr[3]=w; cr[4]=l; cr[5]=h; cr[6]=r; cr[7]=score;
  float sx = fmaxf(w, 0.2f), sy = fmaxf(l, 0.2f), sz = fmaxf(h, 0.2f);
  float* nb = nbox + ((size_t)b*CAP + rk)*8;
  nb[0]=x - sx*0.5f; nb[1]=y - sy*0.5f; nb[2]=z;
  nb[3]=x + sx*0.5f; nb[4]=y + sy*0.5f; nb[5]=z + sz;
  nb[6]=sx*sy*sz;   nb[7]=0.f;
}

// ---- suppression bitmask, col-major mask[b][word c][row i] (proven) ----
__global__ __launch_bounds__(256) void k_mask(const float* __restrict__ nbox,
                                              u64* __restrict__ mask) {
  int c = blockIdx.x;            // word/column block 0..62
  int R = blockIdx.y;            // 256-row tile 0..15
  int b = blockIdx.z;
  if (c < R*4) return;           // tile fully below diagonal: words never read
  __shared__ float4 ca4[64], cb4[64];
  int t = threadIdx.x;
  int j0 = c*64;
  if (t < 64) {
    int j = j0 + t; int jc = j < PRE ? j : 0;
    const float4* p = (const float4*)(nbox + ((size_t)b*CAP + jc)*8);
    ca4[t] = p[0]; cb4[t] = p[1];
  }
  __syncthreads();
  int i = R*256 + t;
  if (i >= PRE) return;
  const float4* rp = (const float4*)(nbox + ((size_t)b*CAP + i)*8);
  float4 A = rp[0], Bv = rp[1];  // A = lo.xyz, hi.x ; Bv = hi.y, hi.z, vol, pad
  u64 bits = 0;
  #pragma unroll
  for (int jj = 0; jj < 64; ++jj) {
    float4 C = ca4[jj], D = cb4[jj];
    float d0 = fminf(A.w,  C.w) - fmaxf(A.x, C.x);
    float d1 = fminf(Bv.x, D.x) - fmaxf(A.y, C.y);
    float d2 = fminf(Bv.y, D.y) - fmaxf(A.z, C.z);
    float inter = fmaxf(d0, 0.f) * fmaxf(d1, 0.f) * fmaxf(d2, 0.f);
    float uni = Bv.z + D.z - inter;
    if (inter > 0.3f * uni) bits |= (1ull << jj);
  }
  int vcols = PRE - j0;                                  // >= 32 for c <= 62
  if (vcols < 64) bits &= ((1ull << vcols) - 1ull);      // clear cols >= PRE
  if (j0 <= i) {                                          // clear cols j <= i
    int d = i - j0;
    if (d >= 63) bits = 0;
    else bits &= ~((2ull << d) - 1ull);
  }
  mask[((size_t)b*MASKW + c)*PRE + i] = bits;
}

// ---- R12: pinned PULL kernel -- install batch b's mask lines in XCD b's L2 ----
// R6 proved locality moves timed k_reduce (~41.5 -> ~19) but paid +42us by
// pinning k_mask's COMPUTE. R7 failed because the prefetch ran concurrently
// with (and competed against) the resolve. This kernel does the line-move as
// its own dispatch: XCD b's 16 blocks sweep rows [0, PULLROWS) of all 64
// word-columns of batch b (1 MB) with massive MLP -- remote-dirty snoops are
// paid latency-PARALLEL here, so k_reduce (block b, same XCD) hits local L2.
// Values sunk via asm (rule #17: keep loads live, no side effects).
__global__ __launch_bounds__(256) void k_pull(const u64* __restrict__ mask) {
  int xcd = blockIdx.x;                // XCD pin; 4..7 idle-exit
  if (xcd >= BB) return;
  int b = xcd;
  int seg = blockIdx.y;                // 0..15: 4 word-columns each
  int t = threadIdx.x;
  const char* base = (const char*)(mask + (size_t)b*MASKW*PRE);
  u64 acc = 0;
  #pragma unroll
  for (int s = 0; s < 4; ++s) {
    int c = seg*4 + s;
    const ulonglong2* p = (const ulonglong2*)(base + (size_t)c*PRE*8);
    #pragma unroll
    for (int k = 0; k < 4; ++k) {      // PULLROWS*8B = 16KB = 1024 x 16B
      ulonglong2 v = p[(size_t)k*256 + t];
      acc ^= v.x ^ v.y;
    }
  }
  asm volatile("" :: "v"(acc));        // sink
}

// ---- greedy NMS reduce, 32-row chunked double-buffer (R5 exact, timed-best) ----
// R11's asm pipeline crashed (VGPR-pressure spills corrupt async asm outputs
// and hand vmcnt counts); reverted. The locality lever (k_pull) now runs as a
// separate dispatch, so this kernel's ~16-load batches hit LOCAL XCD L2.
__device__ __forceinline__ void load_chunk(u64 (&buf)[32], const u64* col,
                                           int c, int lane) {
  bool act = lane >= (c >> 1);           // words < row>>6 never written
  const ulonglong2* p = (const ulonglong2*)(col + c*32);
  #pragma unroll
  for (int k = 0; k < 16; ++k) {
    ulonglong2 v; v.x = 0; v.y = 0;
    if (act) v = p[k];
    buf[2*k] = v.x; buf[2*k+1] = v.y;
  }
}

__device__ __forceinline__ void resolve_chunk(u64 (&buf)[32], int c, int lane,
                                              u64& removed, int& kc,
                                              int* __restrict__ sel_lds) {
  int wq = c >> 1;
  int base = (c & 1) * 32;               // bit window of word wq for this chunk
  u64 cur = removed, km = 0;
  #pragma unroll
  for (int jj = 0; jj < 32; ++jj) {
    if (((cur >> (base + jj)) & 1ull) == 0ull) {
      km |= (1ull << (base + jj));
      cur |= buf[jj];
    }
  }
  u64 kmw = __shfl(km, wq, 64);          // only lane wq's km is meaningful
  #pragma unroll
  for (int jj = 0; jj < 32; ++jj) {
    if ((kmw >> (base + jj)) & 1ull) removed |= buf[jj];
  }
  int sh = base + (lane & 31);           // <= 63: no UB shift
  bool mine = (lane < 32) && ((kmw >> sh) & 1ull);
  int pos = kc + (int)__popcll(kmw & ((1ull << sh) - 1ull));
  if (mine && pos < POST) sel_lds[pos] = c*32 + lane;
  kc += (int)__popcll(kmw);              // uniform across wave
}

__global__ __launch_bounds__(64) void k_reduce(const u64* __restrict__ mask,
                                               const float* __restrict__ crow,
                                               float* __restrict__ out) {
  __shared__ int sel_lds[POST];
  int b = blockIdx.x, lane = threadIdx.x;
  const u64* col = mask + ((size_t)b*MASKW + lane)*PRE;   // this lane's word-column
  u64 bufA[32], bufB[32];
  u64 removed = 0;
  int kc = 0;
  load_chunk(bufA, col, 0, lane);
  for (int c = 0; c < NCHUNK; c += 2) {
    if (c + 1 < NCHUNK) load_chunk(bufB, col, c + 1, lane);   // prefetch
    resolve_chunk(bufA, c, lane, removed, kc, sel_lds);
    if (kc >= POST) break;
    if (c + 1 >= NCHUNK) break;
    if (c + 2 < NCHUNK) load_chunk(bufA, col, c + 2, lane);   // prefetch
    resolve_chunk(bufB, c + 1, lane, removed, kc, sel_lds);
    if (kc >= POST) break;
  }
  __syncthreads();
  int kcap = kc < POST ? kc : POST;
  for (int r = lane; r < POST; r += 64) {
    float4 o0 = make_float4(0.f,0.f,0.f,0.f), o1 = o0;
    if (r < kcap) {
      int i = sel_lds[r];
      const float4* p = (const float4*)(crow + ((size_t)b*CAP + i)*8);
      o0 = p[0]; o1 = p[1];
    }
    float4* q = (float4*)(out + ((size_t)b*POST + r)*8);
    q[0] = o0; q[1] = o1;
  }
}

extern "C" void kernel_launch(void* const* d_in, const int* in_sizes, int n_in,
                              void* d_out, int out_size, void* d_ws, size_t ws_size,
                              hipStream_t stream) {
  const float* obj = (const float*)d_in[0];   // (N,)
  const float* reg = (const float*)d_in[1];   // (N,7)
  const float* anc = (const float*)d_in[2];   // (N,7)
  float* out = (float*)d_out;                 // (4,1000,8)
  char* ws = (char*)d_ws;

  int*  cntG = (int*)(ws + OFF_CNTG);
  int*  cntE = (int*)(ws + OFF_CNTE);
  u64*  keys = (u64*)(ws + OFF_KEYS);
  u32*  rank = (u32*)(ws + OFF_RANK);
  u32*  hc   = (u32*)(ws + OFF_HC);
  u32*  hf   = (u32*)(ws + OFF_HF);
  float* crow = (float*)(ws + OFF_CROW);
  float* nbox = (float*)(ws + OFF_NBOX);
  u64*  mask = (u64*)(ws + OFF_MASK);

  // 8 launches (R5 structure + k_pull). R12: the line-move to k_reduce's XCD
  // runs as its own massively-parallel pinned dispatch between mask and reduce.
  k_hcoarse<<<NN/4096, 256, 0, stream>>>(obj, hc, (u64*)ws);
  k_hfine<<<NN/4096, 256, 0, stream>>>(obj, hc, hf);
  k_compact<<<NN/4096, 256, 0, stream>>>(obj, hc, hf, cntG, cntE, keys);
  k_rankp<<<dim3(CAPR/64, RSLICE, BB), 64, 0, stream>>>(keys, rank);
  k_decode<<<(BB*CAPR)/256, 256, 0, stream>>>(keys, rank, reg, anc, crow, nbox);
  k_mask<<<dim3(NBLK, 16, BB), 256, 0, stream>>>(nbox, mask);
  k_pull<<<dim3(8, 16), 256, 0, stream>>>(mask);
  k_reduce<<<BB, 64, 0, stream>>>(mask, crow, out);
}